// Round 1
// baseline (9.377 us; speedup 1.0000x reference)
//
#include <hip/hip_runtime.h>

// AttentionLayer (AFM-style) on MI355X.
//
// Key identity: softmax over a size-1 axis == 1.0, so the attention MLP is
// mathematically dead. Output reduces to the pairwise-product pooling:
//   afm[b,e] = sum_{i<j} x[b,i,e]*x[b,j,e]
//            = 0.5 * ( (sum_f x[b,f,e])^2 - sum_f x[b,f,e]^2 )
// This is a pure streaming reduction over F (=50) per (b,e) column.

template <int F>
__global__ __launch_bounds__(256) void afm_sum_kernel(const float* __restrict__ x,
                                                      float* __restrict__ out,
                                                      int B, int E) {
    const int ecols = E >> 1;  // float2 columns per row
    const int total = B * ecols;
    int tid = blockIdx.x * blockDim.x + threadIdx.x;
    if (tid >= total) return;
    int b = tid / ecols;
    int c = tid - b * ecols;

    const float2* xp = reinterpret_cast<const float2*>(x) + (size_t)b * F * ecols + c;

    float2 s  = make_float2(0.f, 0.f);
    float2 ss = make_float2(0.f, 0.f);
#pragma unroll
    for (int f = 0; f < F; ++f) {
        float2 v = xp[(size_t)f * ecols];
        s.x += v.x;
        s.y += v.y;
        ss.x = fmaf(v.x, v.x, ss.x);
        ss.y = fmaf(v.y, v.y, ss.y);
    }

    float2 o;
    o.x = 0.5f * (s.x * s.x - ss.x);
    o.y = 0.5f * (s.y * s.y - ss.y);
    reinterpret_cast<float2*>(out)[tid] = o;
}

// Fallback for unexpected F (runtime loop, partially unrolled).
__global__ __launch_bounds__(256) void afm_sum_generic(const float* __restrict__ x,
                                                       float* __restrict__ out,
                                                       int B, int E, int F) {
    const int ecols = E >> 1;
    const int total = B * ecols;
    int tid = blockIdx.x * blockDim.x + threadIdx.x;
    if (tid >= total) return;
    int b = tid / ecols;
    int c = tid - b * ecols;

    const float2* xp = reinterpret_cast<const float2*>(x) + (size_t)b * F * ecols + c;

    float2 s  = make_float2(0.f, 0.f);
    float2 ss = make_float2(0.f, 0.f);
#pragma unroll 10
    for (int f = 0; f < F; ++f) {
        float2 v = xp[(size_t)f * ecols];
        s.x += v.x;
        s.y += v.y;
        ss.x = fmaf(v.x, v.x, ss.x);
        ss.y = fmaf(v.y, v.y, ss.y);
    }

    float2 o;
    o.x = 0.5f * (s.x * s.x - ss.x);
    o.y = 0.5f * (s.y * s.y - ss.y);
    reinterpret_cast<float2*>(out)[tid] = o;
}

extern "C" void kernel_launch(void* const* d_in, const int* in_sizes, int n_in,
                              void* d_out, int out_size, void* d_ws, size_t ws_size,
                              hipStream_t stream) {
    const float* x = (const float*)d_in[0];  // [B, F, E] float32
    float* out = (float*)d_out;              // [B, E] float32

    // Recover dims from sizes:
    //   in_sizes[0] = B*F*E, in_sizes[1] = E*A, in_sizes[2] = A, in_sizes[3] = A
    //   out_size    = B*E
    const int A = in_sizes[2];
    const int E = in_sizes[1] / A;
    const int B = out_size / E;
    const int F = in_sizes[0] / (B * E);

    const int total = B * (E >> 1);
    const int block = 256;
    const int grid = (total + block - 1) / block;

    if (F == 50) {
        afm_sum_kernel<50><<<grid, block, 0, stream>>>(x, out, B, E);
    } else {
        afm_sum_generic<<<grid, block, 0, stream>>>(x, out, B, E, F);
    }
}